// Round 13
// baseline (489.365 us; speedup 1.0000x reference)
//
#include <hip/hip_runtime.h>
#include <hip/hip_bf16.h>
#include <stdint.h>
#include <math.h>

typedef __attribute__((ext_vector_type(8))) short bf16x8;
typedef __attribute__((ext_vector_type(4))) float f32x4;

#define D_K 256
#define JCHUNK 1024
#define BN 32
#define NT (JCHUNK / BN)    // 32 tiles per block

__device__ __forceinline__ unsigned short f2bf(float f) {
    unsigned u = __float_as_uint(f);
    u += 0x7fffu + ((u >> 16) & 1u);   // round-to-nearest-even
    return (unsigned short)(u >> 16);
}

__device__ __forceinline__ void gload_lds16(const void* g, void* l) {
    __builtin_amdgcn_global_load_lds(
        (const __attribute__((address_space(1))) void*)g,
        (__attribute__((address_space(3))) void*)l,
        16, 0, 0);
}

// ---------------- Kernel 1: row-normalize z -> bf16; zero partials ----------------
__global__ void normalize_k(const float* __restrict__ z,
                            unsigned short* __restrict__ zn,
                            float* __restrict__ part, int N) {
    int gid  = blockIdx.x * blockDim.x + threadIdx.x;
    if (gid < 5 * N) part[gid] = 0.f;      // stream-ordered before fused_k
    int gw   = gid >> 6;                   // one wave per row
    int lane = threadIdx.x & 63;
    if (gw >= N) return;
    float4 v = reinterpret_cast<const float4*>(z + (size_t)gw * D_K)[lane];
    float ss = v.x * v.x + v.y * v.y + v.z * v.z + v.w * v.w;
#pragma unroll
    for (int m = 32; m; m >>= 1) ss += __shfl_xor(ss, m);
    float sc = 1.0f / fmaxf(sqrtf(ss), 1e-8f);
    ushort4 o;
    o.x = f2bf(v.x * sc); o.y = f2bf(v.y * sc);
    o.z = f2bf(v.z * sc); o.w = f2bf(v.w * sc);
    reinterpret_cast<ushort4*>(zn + (size_t)gw * D_K)[lane] = o;
}

// Stage one 32-row x 256-d bf16 zn tile (16 KB) into LDS in [kslot][row][16B]
__device__ __forceinline__ void stage_zn(char* dst, const unsigned short* zn,
                                         int j0, int tid, int wid) {
#pragma unroll
    for (int it = 0; it < 4; ++it) {
        int li    = it * 4096 + tid * 16;
        int kslot = li >> 9;          // 0..31
        int row   = (li >> 4) & 31;   // 0..31
        const char* src = reinterpret_cast<const char*>(zn) +
                          ((size_t)(j0 + row) << 9) + (size_t)kslot * 16;
        gload_lds16(src, dst + it * 4096 + wid * 1024);
    }
}

// ---------------- Kernel 2: fused sim-GEMM + row reductions (R12, unchanged) ------
__global__ __launch_bounds__(256, 4) void fused_k(
    const unsigned short* __restrict__ zn,
    const float* __restrict__ adj,
    const float* __restrict__ tsim,
    float* __restrict__ part, int N) {
    __shared__ alignas(128) char L[2][BN * 512];   // 2 x 16 KB

    const float INV_T = 1.0f / 0.07f;
    const int NIB = N >> 6;
    int ib  = blockIdx.x & (NIB - 1);
    int jc  = blockIdx.x / NIB;
    int tid = threadIdx.x;
    int wid = tid >> 6, lane = tid & 63;
    int l15 = lane & 15, lhi = lane >> 4;
    int gi  = ib * 64 + wid * 16 + l15;
    int jbase = jc * JCHUNK;

    bf16x8 bfr[8];
    {
        const bf16x8* bp = reinterpret_cast<const bf16x8*>(zn + (size_t)gi * D_K) + lhi;
#pragma unroll
        for (int ks = 0; ks < 8; ++ks) bfr[ks] = bp[ks * 4];
    }

    float accden = 0.f, accs1 = 0.f, acca = 0.f, acct1 = 0.f, acctt = 0.f;

    const float* abase = adj  + (size_t)gi * N + jbase + lhi * 4;
    const float* tbase = tsim + (size_t)gi * N + jbase + lhi * 4;

    stage_zn(L[0], zn, jbase, tid, wid);
    __builtin_amdgcn_sched_barrier(0);
    f32x4 av[2], tv[2];
#pragma unroll
    for (int t = 0; t < 2; ++t) {
        av[t] = __builtin_nontemporal_load(reinterpret_cast<const f32x4*>(abase + t * 16));
        tv[t] = __builtin_nontemporal_load(reinterpret_cast<const f32x4*>(tbase + t * 16));
    }
    asm volatile("s_waitcnt vmcnt(4)" ::: "memory");
    __builtin_amdgcn_s_barrier();

    for (int jt = 0; jt < NT; ++jt) {
        const char* buf = L[jt & 1];

        f32x4 nav[2], ntv[2];
        if (jt + 1 < NT) {
            stage_zn(L[(jt & 1) ^ 1], zn, jbase + (jt + 1) * BN, tid, wid);
            __builtin_amdgcn_sched_barrier(0);
            const float* an = abase + (jt + 1) * BN;
            const float* tn = tbase + (jt + 1) * BN;
#pragma unroll
            for (int t = 0; t < 2; ++t) {
                nav[t] = __builtin_nontemporal_load(reinterpret_cast<const f32x4*>(an + t * 16));
                ntv[t] = __builtin_nontemporal_load(reinterpret_cast<const f32x4*>(tn + t * 16));
            }
        }

        f32x4 acc[2] = {(f32x4){0.f,0.f,0.f,0.f}, (f32x4){0.f,0.f,0.f,0.f}};
#pragma unroll
        for (int ks = 0; ks < 8; ++ks) {
#pragma unroll
            for (int t = 0; t < 2; ++t) {
                int boff = (ks << 11) + (lhi << 9) + (t << 8) + (l15 << 4);
                bf16x8 aj = *reinterpret_cast<const bf16x8*>(buf + boff);
                acc[t] = __builtin_amdgcn_mfma_f32_16x16x32_bf16(aj, bfr[ks], acc[t], 0, 0, 0);
            }
        }

        int j0 = jbase + jt * BN;
#pragma unroll
        for (int t = 0; t < 2; ++t) {
            int gj0 = j0 + t * 16 + lhi * 4;
#pragma unroll
            for (int r = 0; r < 4; ++r) {
                float sim = acc[t][r] * INV_T;
                float e   = (gi == gj0 + r) ? 0.f : __expf(sim);
                float a   = av[t][r];
                float w   = tv[t][r];
                accden += e;
                accs1 = fmaf(a, sim, accs1);  acca  += a;
                acct1 = fmaf(w, sim, acct1);  acctt += w;
            }
        }
        if (jt + 1 < NT) {
#pragma unroll
            for (int t = 0; t < 2; ++t) { av[t] = nav[t]; tv[t] = ntv[t]; }
        }

        asm volatile("s_waitcnt vmcnt(4)" ::: "memory");
        __builtin_amdgcn_s_barrier();
    }

    accden += __shfl_xor(accden, 16); accden += __shfl_xor(accden, 32);
    accs1  += __shfl_xor(accs1, 16);  accs1  += __shfl_xor(accs1, 32);
    acca   += __shfl_xor(acca, 16);   acca   += __shfl_xor(acca, 32);
    acct1  += __shfl_xor(acct1, 16);  acct1  += __shfl_xor(acct1, 32);
    acctt  += __shfl_xor(acctt, 16);  acctt  += __shfl_xor(acctt, 32);
    if (lhi == 0) {
        atomicAdd(part + gi, accden);
        atomicAdd(part + (size_t)N + gi, accs1);
        atomicAdd(part + (size_t)2 * N + gi, acca);
        atomicAdd(part + (size_t)3 * N + gi, acct1);
        atomicAdd(part + (size_t)4 * N + gi, acctt);
    }
}

// ---------------- Kernel 3: finalize scalar ----------------
__global__ void finalize_k(const float* __restrict__ part, float* __restrict__ out, int N) {
    const float* den = part;
    const float* s1  = part + (size_t)N;
    const float* aa  = part + (size_t)2 * N;
    const float* t1  = part + (size_t)3 * N;
    const float* tt  = part + (size_t)4 * N;
    float acc = 0.f;
    for (int i = threadIdx.x; i < N; i += blockDim.x) {
        float ld = logf(den[i] + 1e-8f);
        acc += -(s1[i] - ld * aa[i]) / (aa[i] + 1e-8f)
               - (t1[i] - ld * tt[i]) / (tt[i] + 1e-8f);
    }
#pragma unroll
    for (int m = 32; m; m >>= 1) acc += __shfl_xor(acc, m);
    __shared__ float red[16];
    if ((threadIdx.x & 63) == 0) red[threadIdx.x >> 6] = acc;
    __syncthreads();
    if (threadIdx.x == 0) {
        float tot = 0.f;
        int nw = blockDim.x >> 6;
        for (int w = 0; w < nw; ++w) tot += red[w];
        out[0] = tot / (float)N;
    }
}

// =============== DIAGNOSTIC PROBES (load-only, asm-kept-live, no stores) ===========
// D1/D2: exact fused_k stream addressing (128B per row-visit, 32KB row stride),
//        16 loads/wave in flight. D1 = nontemporal, D2 = plain.
template <int USE_NT>
__global__ __launch_bounds__(256) void diag_pattern_k(
    const float* __restrict__ adj, const float* __restrict__ tsim, int N) {
    const int NIB = N >> 6;
    int ib  = blockIdx.x & (NIB - 1);
    int jc  = blockIdx.x / NIB;
    int tid = threadIdx.x;
    int wid = tid >> 6, lane = tid & 63;
    int l15 = lane & 15, lhi = lane >> 4;
    int gi  = ib * 64 + wid * 16 + l15;
    const float* ab = adj  + (size_t)gi * N + jc * JCHUNK + lhi * 4;
    const float* tb = tsim + (size_t)gi * N + jc * JCHUNK + lhi * 4;
    f32x4 s0 = {0,0,0,0}, s1 = {0,0,0,0}, s2 = {0,0,0,0}, s3 = {0,0,0,0};
    for (int jt = 0; jt < 32; jt += 4) {
        f32x4 v[16];
#pragma unroll
        for (int u = 0; u < 4; ++u) {
            const float* a = ab + (jt + u) * 32;
            const float* t = tb + (jt + u) * 32;
            if (USE_NT) {
                v[u*4+0] = __builtin_nontemporal_load(reinterpret_cast<const f32x4*>(a));
                v[u*4+1] = __builtin_nontemporal_load(reinterpret_cast<const f32x4*>(a + 16));
                v[u*4+2] = __builtin_nontemporal_load(reinterpret_cast<const f32x4*>(t));
                v[u*4+3] = __builtin_nontemporal_load(reinterpret_cast<const f32x4*>(t + 16));
            } else {
                v[u*4+0] = *reinterpret_cast<const f32x4*>(a);
                v[u*4+1] = *reinterpret_cast<const f32x4*>(a + 16);
                v[u*4+2] = *reinterpret_cast<const f32x4*>(t);
                v[u*4+3] = *reinterpret_cast<const f32x4*>(t + 16);
            }
        }
#pragma unroll
        for (int u = 0; u < 4; ++u) {
            s0 += v[u*4+0]; s1 += v[u*4+1]; s2 += v[u*4+2]; s3 += v[u*4+3];
        }
    }
    f32x4 s = (s0 + s1) + (s2 + s3);
    float r = (s[0] + s[1]) + (s[2] + s[3]);
    asm volatile("" :: "v"(r));     // keep loads live (rule #17), no store
}

// D3: fully-contiguous wave reads (each wave-instr = one 1KB segment), 16 deep.
__global__ __launch_bounds__(256) void diag_contig_k(
    const float* __restrict__ adj, const float* __restrict__ tsim, int N) {
    size_t per = ((size_t)N * N) / gridDim.x;          // 65536 floats per block
    const float* ab = adj  + (size_t)blockIdx.x * per;
    const float* tb = tsim + (size_t)blockIdx.x * per;
    int tid = threadIdx.x;
    f32x4 s0 = {0,0,0,0}, s1 = {0,0,0,0};
    for (int it = 0; it < 64; it += 8) {
        f32x4 v[16];
#pragma unroll
        for (int u = 0; u < 8; ++u) {
            v[u]     = *reinterpret_cast<const f32x4*>(ab + (size_t)(it + u) * 1024 + tid * 4);
            v[8 + u] = *reinterpret_cast<const f32x4*>(tb + (size_t)(it + u) * 1024 + tid * 4);
        }
#pragma unroll
        for (int u = 0; u < 8; ++u) { s0 += v[u]; s1 += v[8 + u]; }
    }
    f32x4 s = s0 + s1;
    float r = (s[0] + s[1]) + (s[2] + s[3]);
    asm volatile("" :: "v"(r));
}

extern "C" void kernel_launch(void* const* d_in, const int* in_sizes, int n_in,
                              void* d_out, int out_size, void* d_ws, size_t ws_size,
                              hipStream_t stream) {
    const float* z    = (const float*)d_in[0];
    const float* adj  = (const float*)d_in[1];
    const float* tsim = (const float*)d_in[2];

    int N = (int)(sqrt((double)in_sizes[1]) + 0.5);  // 8192

    unsigned short* zn = (unsigned short*)d_ws;                   // 4 MB
    float* part = (float*)((char*)d_ws + (size_t)N * D_K * 2);    // 5*N f32

    normalize_k<<<N / 4, 256, 0, stream>>>(z, zn, part, N);

    int nblocks = (N >> 6) * (N / JCHUNK);  // 1024
    fused_k<<<nblocks, 256, 0, stream>>>(zn, adj, tsim, part, N);

    finalize_k<<<1, 1024, 0, stream>>>(part, (float*)d_out, N);

    // ---- diagnostics (output-neutral; profiled as separate dispatches) ----
    diag_pattern_k<1><<<nblocks, 256, 0, stream>>>(adj, tsim, N);  // D1: pattern, NT
    diag_pattern_k<0><<<nblocks, 256, 0, stream>>>(adj, tsim, N);  // D2: pattern, plain
    diag_contig_k<<<nblocks, 256, 0, stream>>>(adj, tsim, N);      // D3: contiguous
}

// Round 14
// 210.283 us; speedup vs baseline: 2.3272x; 2.3272x over previous
//
#include <hip/hip_runtime.h>
#include <hip/hip_bf16.h>
#include <stdint.h>
#include <math.h>

typedef __attribute__((ext_vector_type(8))) short bf16x8;
typedef __attribute__((ext_vector_type(4))) float f32x4;

#define D_K 256
#define JCHUNK 2048
#define SB 256              // superblock j-width
#define NSB (JCHUNK / SB)   // 8
#define NST (SB / 16)       // 16 MFMA subtiles per superblock

__device__ __forceinline__ unsigned short f2bf(float f) {
    unsigned u = __float_as_uint(f);
    u += 0x7fffu + ((u >> 16) & 1u);   // round-to-nearest-even
    return (unsigned short)(u >> 16);
}
__device__ __forceinline__ float bf2f(unsigned short u) {
    return __uint_as_float(((unsigned)u) << 16);
}

// ---------------- Kernel 1: row-normalize z -> bf16; zero partials ----------------
__global__ void normalize_k(const float* __restrict__ z,
                            unsigned short* __restrict__ zn,
                            float* __restrict__ part, int N) {
    int gid  = blockIdx.x * blockDim.x + threadIdx.x;
    if (gid < 5 * N) part[gid] = 0.f;      // stream-ordered before fused_k
    int gw   = gid >> 6;                   // one wave per row
    int lane = threadIdx.x & 63;
    if (gw >= N) return;
    float4 v = reinterpret_cast<const float4*>(z + (size_t)gw * D_K)[lane];
    float ss = v.x * v.x + v.y * v.y + v.z * v.z + v.w * v.w;
#pragma unroll
    for (int m = 32; m; m >>= 1) ss += __shfl_xor(ss, m);
    float sc = 1.0f / fmaxf(sqrtf(ss), 1e-8f);
    ushort4 o;
    o.x = f2bf(v.x * sc); o.y = f2bf(v.y * sc);
    o.z = f2bf(v.z * sc); o.w = f2bf(v.w * sc);
    reinterpret_cast<ushort4*>(zn + (size_t)gw * D_K)[lane] = o;
}

// ---------------- Kernel 2: pack zn into MFMA A-fragment order (R10-verified) ------
// znp 16B-chunk index = jg*512 + ks*64 + lane, holding
// zn[jg*16 + (lane&15)][ks*32 + (lane>>4)*8 .. +8]
__global__ void pack_k(const unsigned short* __restrict__ zn,
                       unsigned short* __restrict__ znp, int N) {
    int jg = blockIdx.x;
    int t  = threadIdx.x;
    const unsigned short* src = zn + (size_t)jg * 16 * D_K;
    unsigned short* dst = znp + (size_t)jg * 4096;
#pragma unroll
    for (int h = 0; h < 2; ++h) {
        int p  = t + h * 256;          // 0..511
        int ks = p >> 6;
        int l  = p & 63;
        bf16x8 v = *reinterpret_cast<const bf16x8*>(
            src + (l & 15) * D_K + ks * 32 + (l >> 4) * 8);
        *reinterpret_cast<bf16x8*>(dst + (size_t)p * 8) = v;
    }
}

// ---------------- Kernel 3: two-phase fused kernel, zero barriers ----------------
// Wave owns 16 i-rows x JCHUNK j. Per 256-j superblock:
//  phase 1 (R10-verified): af = 1KB coalesced loads from L2-resident znp;
//          MFMA vs persistent i-frags; exp->accden; park sim bf16 in
//          wave-private LDS [16 i][256 j] (XOR-swizzled).
//  phase 2 (D3 shape): per i-row, ONE f32x4/lane = 1KB CONTIGUOUS read of that
//          row's adj & tsim chunk; dot vs parked sim (8B LDS reads);
//          per-row register accumulators (static idx).
// part: [0,N) den | [N,2N) S1 | [2N,3N) A | [3N,4N) T1 | [4N,5N) T
__global__ __launch_bounds__(256, 2) void fused_k(
    const unsigned short* __restrict__ zn,
    const unsigned short* __restrict__ znp,
    const float* __restrict__ adj,
    const float* __restrict__ tsim,
    float* __restrict__ part, int N) {
    __shared__ alignas(128) char parkL[4][16 * 512];   // 4 waves x 8 KB

    const float INV_T = 1.0f / 0.07f;
    const int NIB = N >> 6;                // 128
    int ib  = blockIdx.x & (NIB - 1);
    int jc  = blockIdx.x / NIB;            // 0..3
    int tid = threadIdx.x;
    int wid = tid >> 6, lane = tid & 63;
    int l15 = lane & 15, lhi = lane >> 4;
    int i0w = ib * 64 + wid * 16;
    int gi  = i0w + l15;                   // phase-1 output col = i-row
    int jb  = jc * JCHUNK;
    char* parkW = parkL[wid];

    // persistent B-operand fragments: zn row gi (32 VGPRs)
    bf16x8 bfr[8];
    {
        const bf16x8* bp = reinterpret_cast<const bf16x8*>(zn + (size_t)gi * D_K) + lhi;
#pragma unroll
        for (int ks = 0; ks < 8; ++ks) bfr[ks] = bp[ks * 4];
    }

    float accden = 0.f;
    // per-row accumulators (all statically indexed; 64 VGPRs)
    float rs1[16], rt1[16], ra[16], rt[16];
#pragma unroll
    for (int r = 0; r < 16; ++r) { rs1[r] = 0.f; rt1[r] = 0.f; ra[r] = 0.f; rt[r] = 0.f; }

    for (int sb = 0; sb < NSB; ++sb) {
        int jsb = jb + sb * SB;

        // ---------- phase 1: sim for 16 i x 256 j (R10-verified path) ----------
#pragma unroll 2
        for (int st = 0; st < NST; ++st) {
            int j0 = jsb + st * 16;
            const bf16x8* ap = reinterpret_cast<const bf16x8*>(znp) +
                               ((size_t)(j0 >> 4) << 9) + lane;
            bf16x8 af[8];
#pragma unroll
            for (int ks = 0; ks < 8; ++ks) af[ks] = ap[ks * 64];  // 1KB coalesced each
            f32x4 acc = (f32x4){0.f, 0.f, 0.f, 0.f};
#pragma unroll
            for (int ks = 0; ks < 8; ++ks)
                acc = __builtin_amdgcn_mfma_f32_16x16x32_bf16(af[ks], bfr[ks], acc, 0, 0, 0);
            // lane holds sim[j = j0+lhi*4+r][i = gi]
            int jcol = st * 16 + lhi * 4;
            float sv[4];
#pragma unroll
            for (int r = 0; r < 4; ++r) {
                sv[r] = acc[r] * INV_T;
                accden += (gi == j0 + lhi * 4 + r) ? 0.f : __expf(sv[r]);
            }
            ushort4 pk;
            pk.x = f2bf(sv[0]); pk.y = f2bf(sv[1]);
            pk.z = f2bf(sv[2]); pk.w = f2bf(sv[3]);
            *reinterpret_cast<ushort4*>(
                parkW + l15 * 512 + ((jcol * 2) ^ ((l15 & 7) << 4))) = pk;
        }

        // same-wave DS write->read ordering fence
        asm volatile("s_waitcnt lgkmcnt(0)" ::: "memory");
        __builtin_amdgcn_sched_barrier(0);

        // ---------- phase 2: D3-shape streams — 1KB contiguous per row ----------
        // row r: lane reads adj[i0w+r][jsb + lane*4 .. +4] (wave = 1024B contig)
#pragma unroll
        for (int r0 = 0; r0 < 16; r0 += 4) {
            f32x4 a_[4], t_[4];
#pragma unroll
            for (int u = 0; u < 4; ++u) {
                int row = r0 + u;
                const float* arp = adj  + (size_t)(i0w + row) * N + jsb + lane * 4;
                const float* trp = tsim + (size_t)(i0w + row) * N + jsb + lane * 4;
                a_[u] = *reinterpret_cast<const f32x4*>(arp);
                t_[u] = *reinterpret_cast<const f32x4*>(trp);
            }
#pragma unroll
            for (int u = 0; u < 4; ++u) {
                int row = r0 + u;
                ushort4 s4 = *reinterpret_cast<const ushort4*>(
                    parkW + row * 512 + ((lane * 8) ^ ((row & 7) << 4)));
                float s0 = bf2f(s4.x), s1 = bf2f(s4.y), s2 = bf2f(s4.z), s3 = bf2f(s4.w);
                rs1[row] = fmaf(a_[u][0], s0, fmaf(a_[u][1], s1,
                           fmaf(a_[u][2], s2, fmaf(a_[u][3], s3, rs1[row]))));
                rt1[row] = fmaf(t_[u][0], s0, fmaf(t_[u][1], s1,
                           fmaf(t_[u][2], s2, fmaf(t_[u][3], s3, rt1[row]))));
                ra[row] += (a_[u][0] + a_[u][1]) + (a_[u][2] + a_[u][3]);
                rt[row] += (t_[u][0] + t_[u][1]) + (t_[u][2] + t_[u][3]);
            }
        }
        // LDS in-order per wave: phase-2 reads retire before next phase-1 writes
    }

    // ---------- final reductions + atomics ----------
    accden += __shfl_xor(accden, 16); accden += __shfl_xor(accden, 32);
    if (lhi == 0) atomicAdd(part + gi, accden);
#pragma unroll
    for (int r = 0; r < 16; ++r) {
        float s = rs1[r], a = ra[r], u = rt1[r], w = rt[r];
#pragma unroll
        for (int m = 1; m < 64; m <<= 1) {
            s += __shfl_xor(s, m); a += __shfl_xor(a, m);
            u += __shfl_xor(u, m); w += __shfl_xor(w, m);
        }
        if (lane == 0) {
            int gr = i0w + r;
            atomicAdd(part + (size_t)N + gr, s);
            atomicAdd(part + (size_t)2 * N + gr, a);
            atomicAdd(part + (size_t)3 * N + gr, u);
            atomicAdd(part + (size_t)4 * N + gr, w);
        }
    }
}

// ---------------- Kernel 4: finalize scalar ----------------
__global__ void finalize_k(const float* __restrict__ part, float* __restrict__ out, int N) {
    const float* den = part;
    const float* s1  = part + (size_t)N;
    const float* aa  = part + (size_t)2 * N;
    const float* t1  = part + (size_t)3 * N;
    const float* tt  = part + (size_t)4 * N;
    float acc = 0.f;
    for (int i = threadIdx.x; i < N; i += blockDim.x) {
        float ld = logf(den[i] + 1e-8f);
        acc += -(s1[i] - ld * aa[i]) / (aa[i] + 1e-8f)
               - (t1[i] - ld * tt[i]) / (tt[i] + 1e-8f);
    }
#pragma unroll
    for (int m = 32; m; m >>= 1) acc += __shfl_xor(acc, m);
    __shared__ float red[16];
    if ((threadIdx.x & 63) == 0) red[threadIdx.x >> 6] = acc;
    __syncthreads();
    if (threadIdx.x == 0) {
        float tot = 0.f;
        int nw = blockDim.x >> 6;
        for (int w = 0; w < nw; ++w) tot += red[w];
        out[0] = tot / (float)N;
    }
}

extern "C" void kernel_launch(void* const* d_in, const int* in_sizes, int n_in,
                              void* d_out, int out_size, void* d_ws, size_t ws_size,
                              hipStream_t stream) {
    const float* z    = (const float*)d_in[0];
    const float* adj  = (const float*)d_in[1];
    const float* tsim = (const float*)d_in[2];

    int N = (int)(sqrt((double)in_sizes[1]) + 0.5);  // 8192

    unsigned short* zn  = (unsigned short*)d_ws;                                 // 4 MB
    unsigned short* znp = (unsigned short*)((char*)d_ws + (size_t)N * D_K * 2);  // 4 MB
    float* part = (float*)((char*)d_ws + (size_t)2 * N * D_K * 2);               // 5*N f32

    normalize_k<<<N / 4, 256, 0, stream>>>(z, zn, part, N);
    pack_k<<<N / 16, 256, 0, stream>>>(zn, znp, N);

    int nblocks = (N >> 6) * (N / JCHUNK);  // 128 * 4 = 512
    fused_k<<<nblocks, 256, 0, stream>>>(zn, znp, adj, tsim, part, N);

    finalize_k<<<1, 1024, 0, stream>>>(part, (float*)d_out, N);
}

// Round 15
// 192.282 us; speedup vs baseline: 2.5450x; 1.0936x over previous
//
#include <hip/hip_runtime.h>
#include <hip/hip_bf16.h>
#include <stdint.h>
#include <math.h>

typedef __attribute__((ext_vector_type(8))) short bf16x8;
typedef __attribute__((ext_vector_type(4))) float f32x4;

#define D_K 256
#define JCHUNK 2048
#define SB 256              // superblock j-width
#define NSB (JCHUNK / SB)   // 8
#define BT 32               // staged subtile j-width
#define NST (SB / BT)       // 8 subtiles per superblock

__device__ __forceinline__ unsigned short f2bf(float f) {
    unsigned u = __float_as_uint(f);
    u += 0x7fffu + ((u >> 16) & 1u);   // round-to-nearest-even
    return (unsigned short)(u >> 16);
}
__device__ __forceinline__ float bf2f(unsigned short u) {
    return __uint_as_float(((unsigned)u) << 16);
}
__device__ __forceinline__ void gload_lds16(const void* g, void* l) {
    __builtin_amdgcn_global_load_lds(
        (const __attribute__((address_space(1))) void*)g,
        (__attribute__((address_space(3))) void*)l,
        16, 0, 0);
}

// ---------------- Kernel 1: row-normalize z -> bf16; zero partials ----------------
__global__ void normalize_k(const float* __restrict__ z,
                            unsigned short* __restrict__ zn,
                            float* __restrict__ part, int N) {
    int gid  = blockIdx.x * blockDim.x + threadIdx.x;
    if (gid < 5 * N) part[gid] = 0.f;      // stream-ordered before fused_k
    int gw   = gid >> 6;                   // one wave per row
    int lane = threadIdx.x & 63;
    if (gw >= N) return;
    float4 v = reinterpret_cast<const float4*>(z + (size_t)gw * D_K)[lane];
    float ss = v.x * v.x + v.y * v.y + v.z * v.z + v.w * v.w;
#pragma unroll
    for (int m = 32; m; m >>= 1) ss += __shfl_xor(ss, m);
    float sc = 1.0f / fmaxf(sqrtf(ss), 1e-8f);
    ushort4 o;
    o.x = f2bf(v.x * sc); o.y = f2bf(v.y * sc);
    o.z = f2bf(v.z * sc); o.w = f2bf(v.w * sc);
    reinterpret_cast<ushort4*>(zn + (size_t)gw * D_K)[lane] = o;
}

// Stage one 32-row x 256-d bf16 zn tile (16 KB) into LDS in [kslot][row][16B]
// (R6-proven: 0 bank conflicts; gload_lds dest linear, remap on source).
__device__ __forceinline__ void stage_zn(char* dst, const unsigned short* zn,
                                         int j0, int tid, int wid) {
#pragma unroll
    for (int it = 0; it < 4; ++it) {
        int li    = it * 4096 + tid * 16;
        int kslot = li >> 9;          // 0..31
        int row   = (li >> 4) & 31;   // 0..31
        const char* src = reinterpret_cast<const char*>(zn) +
                          ((size_t)(j0 + row) << 9) + (size_t)kslot * 16;
        gload_lds16(src, dst + it * 4096 + wid * 1024);
    }
}

// ---------------- Kernel 2: two-phase fused kernel ----------------
// Per block (4 waves, 64 i, JCHUNK=2048 j), per 256-j superblock (rotated order):
//  phase 1 (R6 staging): 8 staged 32-j subtiles, block-shared via gload_lds
//     (512 MB total L2 traffic, shared x4 waves); each wave MFMAs its 16 i
//     vs staged j; exp->accden; parks sim bf16 in wave-private LDS slice.
//  phase 2 (R14/D3 shape, barrier-free): per i-row ONE f32x4/lane = 1KB
//     contiguous adj/tsim read; dot vs parked sim; register accumulators.
// part: [0,N) den | [N,2N) S1 | [2N,3N) A | [3N,4N) T1 | [4N,5N) T
__global__ __launch_bounds__(256, 2) void fused_k(
    const unsigned short* __restrict__ zn,
    const float* __restrict__ adj,
    const float* __restrict__ tsim,
    float* __restrict__ part, int N) {
    __shared__ alignas(128) char L[2][BT * 512];       // 2 x 16 KB stage
    __shared__ alignas(128) char parkL[4][16 * 512];   // 4 waves x 8 KB park

    const float INV_T = 1.0f / 0.07f;
    const int NIB = N >> 6;                // 128
    int ib  = blockIdx.x & (NIB - 1);
    int jc  = blockIdx.x / NIB;            // 0..3
    int tid = threadIdx.x;
    int wid = tid >> 6, lane = tid & 63;
    int l15 = lane & 15, lhi = lane >> 4;
    int i0w = ib * 64 + wid * 16;
    int gi  = i0w + l15;                   // phase-1 output col = i-row
    int jb  = jc * JCHUNK;
    char* parkW = parkL[wid];
    int sb0 = blockIdx.x & (NSB - 1);      // rotate superblock order per block

    // persistent B-operand fragments: zn row gi (32 VGPRs)
    bf16x8 bfr[8];
    {
        const bf16x8* bp = reinterpret_cast<const bf16x8*>(zn + (size_t)gi * D_K) + lhi;
#pragma unroll
        for (int ks = 0; ks < 8; ++ks) bfr[ks] = bp[ks * 4];
    }

    float accden = 0.f;
    float rs1[16], rt1[16], ra[16], rt[16];
#pragma unroll
    for (int r = 0; r < 16; ++r) { rs1[r] = 0.f; rt1[r] = 0.f; ra[r] = 0.f; rt[r] = 0.f; }

    // prologue: stage subtile 0 of first superblock
    stage_zn(L[0], zn, jb + sb0 * SB, tid, wid);
    int cur = 0;

    for (int s = 0; s < NSB; ++s) {
        int sbi = (sb0 + s) & (NSB - 1);
        int jsb = jb + sbi * SB;

        // ---------- phase 1: sim for 64 i x 256 j (8 staged subtiles) ----------
        for (int st = 0; st < NST; ++st) {
            // current staged tile ready for ALL waves
            asm volatile("s_waitcnt vmcnt(0)" ::: "memory");
            __syncthreads();

            // issue next stage: st+1 within superblock, else subtile 0 of next sb
            if (st + 1 < NST) {
                stage_zn(L[cur ^ 1], zn, jsb + (st + 1) * BT, tid, wid);
            } else if (s + 1 < NSB) {
                int nsb = (sb0 + s + 1) & (NSB - 1);
                stage_zn(L[cur ^ 1], zn, jb + nsb * SB, tid, wid);
            }

            // MFMA: staged 32 j (A) x own 16 i (B)
            const char* buf = L[cur];
            f32x4 acc[2] = {(f32x4){0.f,0.f,0.f,0.f}, (f32x4){0.f,0.f,0.f,0.f}};
#pragma unroll
            for (int ks = 0; ks < 8; ++ks) {
#pragma unroll
                for (int t = 0; t < 2; ++t) {
                    int boff = (ks << 11) + (lhi << 9) + (t << 8) + (l15 << 4);
                    bf16x8 aj = *reinterpret_cast<const bf16x8*>(buf + boff);
                    acc[t] = __builtin_amdgcn_mfma_f32_16x16x32_bf16(aj, bfr[ks], acc[t], 0, 0, 0);
                }
            }

            // exp->den; park sim bf16 (lane holds sim[j=st*32+t*16+lhi*4+r][i=gi])
#pragma unroll
            for (int t = 0; t < 2; ++t) {
                int jcol = st * BT + t * 16 + lhi * 4;   // j within superblock
                float sv[4];
#pragma unroll
                for (int r = 0; r < 4; ++r) {
                    sv[r] = acc[t][r] * INV_T;
                    accden += (gi == jsb + jcol + r) ? 0.f : __expf(sv[r]);
                }
                ushort4 pk;
                pk.x = f2bf(sv[0]); pk.y = f2bf(sv[1]);
                pk.z = f2bf(sv[2]); pk.w = f2bf(sv[3]);
                *reinterpret_cast<ushort4*>(
                    parkW + l15 * 512 + ((jcol * 2) ^ ((l15 & 7) << 4))) = pk;
            }

            // all waves done reading L[cur] before anyone overwrites it next iter
            __syncthreads();
            cur ^= 1;
        }
        // (last subtile issued the stage for the NEXT superblock -> its HBM/L2
        //  latency hides under phase 2's streams)

        // ---------- phase 2: D3-shape streams, barrier-free ----------
        // row r: lane reads adj[i0w+r][jsb + lane*4 ..+4] => 1KB contiguous/wave
#pragma unroll
        for (int r0 = 0; r0 < 16; r0 += 4) {
            f32x4 a_[4], t_[4];
#pragma unroll
            for (int u = 0; u < 4; ++u) {
                int row = r0 + u;
                a_[u] = *reinterpret_cast<const f32x4*>(
                    adj  + (size_t)(i0w + row) * N + jsb + lane * 4);
                t_[u] = *reinterpret_cast<const f32x4*>(
                    tsim + (size_t)(i0w + row) * N + jsb + lane * 4);
            }
#pragma unroll
            for (int u = 0; u < 4; ++u) {
                int row = r0 + u;
                ushort4 s4 = *reinterpret_cast<const ushort4*>(
                    parkW + row * 512 + ((lane * 8) ^ ((row & 7) << 4)));
                float s0 = bf2f(s4.x), s1 = bf2f(s4.y), s2 = bf2f(s4.z), s3 = bf2f(s4.w);
                rs1[row] = fmaf(a_[u][0], s0, fmaf(a_[u][1], s1,
                           fmaf(a_[u][2], s2, fmaf(a_[u][3], s3, rs1[row]))));
                rt1[row] = fmaf(t_[u][0], s0, fmaf(t_[u][1], s1,
                           fmaf(t_[u][2], s2, fmaf(t_[u][3], s3, rt1[row]))));
                ra[row] += (a_[u][0] + a_[u][1]) + (a_[u][2] + a_[u][3]);
                rt[row] += (t_[u][0] + t_[u][1]) + (t_[u][2] + t_[u][3]);
            }
        }
    }

    // ---------- final reductions + atomics ----------
    accden += __shfl_xor(accden, 16); accden += __shfl_xor(accden, 32);
    if (lhi == 0) atomicAdd(part + gi, accden);
#pragma unroll
    for (int r = 0; r < 16; ++r) {
        float s = rs1[r], a = ra[r], u = rt1[r], w = rt[r];
#pragma unroll
        for (int m = 1; m < 64; m <<= 1) {
            s += __shfl_xor(s, m); a += __shfl_xor(a, m);
            u += __shfl_xor(u, m); w += __shfl_xor(w, m);
        }
        if (lane == 0) {
            int gr = i0w + r;
            atomicAdd(part + (size_t)N + gr, s);
            atomicAdd(part + (size_t)2 * N + gr, a);
            atomicAdd(part + (size_t)3 * N + gr, u);
            atomicAdd(part + (size_t)4 * N + gr, w);
        }
    }
}

// ---------------- Kernel 3: finalize scalar ----------------
__global__ void finalize_k(const float* __restrict__ part, float* __restrict__ out, int N) {
    const float* den = part;
    const float* s1  = part + (size_t)N;
    const float* aa  = part + (size_t)2 * N;
    const float* t1  = part + (size_t)3 * N;
    const float* tt  = part + (size_t)4 * N;
    float acc = 0.f;
    for (int i = threadIdx.x; i < N; i += blockDim.x) {
        float ld = logf(den[i] + 1e-8f);
        acc += -(s1[i] - ld * aa[i]) / (aa[i] + 1e-8f)
               - (t1[i] - ld * tt[i]) / (tt[i] + 1e-8f);
    }
#pragma unroll
    for (int m = 32; m; m >>= 1) acc += __shfl_xor(acc, m);
    __shared__ float red[16];
    if ((threadIdx.x & 63) == 0) red[threadIdx.x >> 6] = acc;
    __syncthreads();
    if (threadIdx.x == 0) {
        float tot = 0.f;
        int nw = blockDim.x >> 6;
        for (int w = 0; w < nw; ++w) tot += red[w];
        out[0] = tot / (float)N;
    }
}

extern "C" void kernel_launch(void* const* d_in, const int* in_sizes, int n_in,
                              void* d_out, int out_size, void* d_ws, size_t ws_size,
                              hipStream_t stream) {
    const float* z    = (const float*)d_in[0];
    const float* adj  = (const float*)d_in[1];
    const float* tsim = (const float*)d_in[2];

    int N = (int)(sqrt((double)in_sizes[1]) + 0.5);  // 8192

    unsigned short* zn = (unsigned short*)d_ws;                   // 4 MB
    float* part = (float*)((char*)d_ws + (size_t)N * D_K * 2);    // 5*N f32

    normalize_k<<<N / 4, 256, 0, stream>>>(z, zn, part, N);

    int nblocks = (N >> 6) * (N / JCHUNK);  // 128 * 4 = 512
    fused_k<<<nblocks, 256, 0, stream>>>(zn, adj, tsim, part, N);

    finalize_k<<<1, 1024, 0, stream>>>(part, (float*)d_out, N);
}